// Round 15
// baseline (5806.473 us; speedup 1.0000x reference)
//
#include <hip/hip_runtime.h>
#include <hip/hip_bf16.h>
#include <math.h>

typedef unsigned int u32;

#define B_ 128
#define S_ 128
#define T_ 127
#define D_ 100
#define QN_ 4
#define SN_ 4
#define KC_ 4
#define RK_ 10
#define NEGV -1000000000.0f
#define MAGIC 0x05EAF00D

__device__ __forceinline__ float sigmf(float x) { return 1.0f / (1.0f + expf(-x)); }

__device__ __forceinline__ u32 f2bfbits(float x) {
  __hip_bfloat16 h = __float2bfloat16(x);
  unsigned short s;
  __builtin_memcpy(&s, &h, 2);
  return (u32)s;
}
__device__ __forceinline__ float bflo(u32 w) { return __uint_as_float(w << 16); }
__device__ __forceinline__ float bfhi(u32 w) { return __uint_as_float(w & 0xffff0000u); }

__device__ __forceinline__ void spinflag(int* f) {
  int sp = 0;
  while (__hip_atomic_load(f, __ATOMIC_ACQUIRE, __HIP_MEMORY_SCOPE_AGENT) != MAGIC && sp < (1 << 22)) ++sp;
}

// ---------------------------------------------------------------------------
// Setup (unchanged from R14).
// ---------------------------------------------------------------------------
__global__ __launch_bounds__(256) void setupk(
    const float* Er, const float* W_ih1, const float* b_ih1,
    const float* Wagg, const float* W_last, const float* W_key,
    const float* b_query, const float* W_W, const float* W_query,
    const float* W_hh1, const float* W_hh2, const float* W_ih2,
    const float* b_hh1, const float* b_hh2, const float* b_ih2,
    u32* wih1a2, float* erw, u32* wagg2, u32* wlast2, float* wkeyT,
    float* scal, u32* wcat16, float* bcat)
{
  int gid = blockIdx.x * blockDim.x + threadIdx.x;
  int gsz = gridDim.x * blockDim.x;

  for (int x = gid; x < 15000; x += gsz) {
    int j2 = x / 300, o = x % 300;
    wih1a2[x] = (f2bfbits(W_ih1[o * 200 + 2 * j2 + 1]) << 16) | f2bfbits(W_ih1[o * 200 + 2 * j2]);
  }
  for (int x = gid; x < 600; x += gsz) {
    int r = x / 300, i = x % 300;
    float acc = b_ih1[i];
    for (int j = 0; j < 100; j++) acc += Er[r * 100 + j] * W_ih1[i * 200 + 100 + j];
    erw[x] = acc;
  }
  for (int x = gid; x < 15000; x += gsz) {
    int h = x / 5000, r = x % 5000, j2 = r / 100, i = r % 100;
    wagg2[x] = (f2bfbits(Wagg[h * 10000 + i * 100 + 2 * j2 + 1]) << 16)
             | f2bfbits(Wagg[h * 10000 + i * 100 + 2 * j2]);
  }
  for (int x = gid; x < 5000; x += gsz) {
    int j2 = x / 100, i = x % 100;
    wlast2[x] = (f2bfbits(W_last[i * 100 + 2 * j2 + 1]) << 16) | f2bfbits(W_last[i * 100 + 2 * j2]);
  }
  for (int x = gid; x < 10000; x += gsz) {
    int j = x / 100, i = x % 100;
    wkeyT[j * 100 + i] = W_key[i * 100 + j];
  }
  for (int x = gid; x < 114688; x += gsz) {
    int slot = x / 64, rem = x % 64, sbu = rem / 16, k = rem % 16;
    const float* src = nullptr;
    if (slot < 300)                       src = W_hh1 + (size_t)slot * 100;
    else if (slot < 600)                  src = W_hh2 + (size_t)(slot - 300) * 100;
    else if (slot >= 1024 && slot < 1324) src = W_ih2 + (size_t)(slot - 1024) * 100;
    else if (slot >= 1536 && slot < 1636) src = W_query + (size_t)(slot - 1536) * 100;
    u32 lo = 0, hi = 0;
    if (src) {
      int e0 = 2 * k, e1 = 2 * k + 1;
      if (e0 < 25) lo = f2bfbits(src[sbu * 25 + e0]);
      if (e1 < 25) hi = f2bfbits(src[sbu * 25 + e1]);
    }
    wcat16[x] = (hi << 16) | lo;
  }
  for (int x = gid; x < 1792; x += gsz) {
    float v = 0.f;
    if (x < 300) v = b_hh1[x];
    else if (x < 600) v = b_hh2[x - 300];
    else if (x >= 1024 && x < 1324) v = b_ih2[x - 1024];
    else if (x >= 1536 && x < 1636) v = b_query[x - 1536];
    bcat[x] = v;
  }
  if (gid == 0) {
    float acc = 0.f;
    for (int i = 0; i < 100; i++) acc += tanhf(b_query[i]) * W_W[100 + i];
    scal[0] = acc;
  }
}

// bf16 row-dot helper: dot(unpack(w[0..3]), hr[0..31])
__device__ __forceinline__ float bf16_dot32(const uint4 w[4], const float hr[32]) {
  float a = 0.f;
#pragma unroll
  for (int c = 0; c < 4; ++c) {
    uint4 ww = w[c];
    const int e = c * 8;
    a = fmaf(__uint_as_float(ww.x << 16),         hr[e + 0], a);
    a = fmaf(__uint_as_float(ww.x & 0xffff0000u), hr[e + 1], a);
    a = fmaf(__uint_as_float(ww.y << 16),         hr[e + 2], a);
    a = fmaf(__uint_as_float(ww.y & 0xffff0000u), hr[e + 3], a);
    a = fmaf(__uint_as_float(ww.z << 16),         hr[e + 4], a);
    a = fmaf(__uint_as_float(ww.z & 0xffff0000u), hr[e + 5], a);
    a = fmaf(__uint_as_float(ww.w << 16),         hr[e + 6], a);
    a = fmaf(__uint_as_float(ww.w & 0xffff0000u), hr[e + 7], a);
  }
  return a;
}

// ---------------------------------------------------------------------------
// MEGA kernel: blocks [0,128) = sequential-scan consumers (R13 body + flag
// polls); blocks [128,16384) = phaseA+phaseB producers for (b,t), t-major.
// One 70.4KB LDS blob carved per role -> 2 blocks/CU; producers co-schedule
// beside consumers. Producer: writes gi1/qw/top10, __syncthreads (drain),
// agent-RELEASE flag (L2 writeback). Consumer: agent-ACQUIRE poll (L2 inv)
// folded into S5 (idle lane), bounded spin.
// ---------------------------------------------------------------------------
__global__ __launch_bounds__(1024) void megak(
    const u32* wcat16, const float* bcat,
    const u32* wih1a2, const float* erw, const u32* wagg2, const u32* wlast2,
    const float* wkeyT,
    float* gi1_all, float* qw_all, int* top10_all, int* flags,
    const float* W_W, const float* b_W, const float* b_key, const float* baggf, const float* blastf,
    const float* Eq, const float* Ec, const int* question, const int* response, const int* mask,
    const int* qnb, const int* snb, const int* cidx, const int* cmask,
    const float* h1_init, const float* h2_init, const float* scal,
    float* out)
{
  __shared__ __align__(16) float SMEM[17600];  // 70.4 KB blob
  const int tid = threadIdx.x;
  float* S = SMEM;

  if (blockIdx.x >= B_) {
    // =================== PRODUCER: phaseA + phaseB for one (b,t) ===========
    const int p = blockIdx.x - B_;
    const int t = p / B_, b = p % B_;
    const size_t bt = (size_t)b * T_ + t;

    float* e0 = S;        float* ne0 = S + 100;  float* e1 = S + 200;  float* ne1 = S + 600;
    float* e2 = S + 1000; float* ne2 = S + 2600; float* m3 = S + 4200;
    float* sum4 = S + 5800; float* sum1 = S + 6200; float* emq = S + 6300;
    float* qcf = S + 6400; float* qtl = S + 6900; float* qwp = S + 7400;
    int* ip = (int*)(S + 7424);
    int* l1 = ip; int* l2 = ip + 4; int* l3 = ip + 20; int* ci = ip + 84; int* cm = ip + 88;

    const int qt = question[b * S_ + t];
    const int mt = mask[b * S_ + t];
    const int rt = response[b * S_ + t];
    const bool act = (mt != 0);

    if (act) {
      if (tid < 4) l1[tid] = qnb[qt * QN_ + tid];
      for (int x = tid; x < 100; x += 1024) e0[x] = Eq[(size_t)qt * 100 + x];
    }
    __syncthreads();
    if (act) {
      if (tid < 16) l2[tid] = snb[l1[tid >> 2] * SN_ + (tid & 3)];
      for (int x = tid; x < 400; x += 1024) e1[x] = Ec[(size_t)l1[x / 100] * 100 + (x % 100)];
    }
    __syncthreads();
    if (act) {
      if (tid < 64) l3[tid] = qnb[l2[tid >> 2] * QN_ + (tid & 3)];
      for (int x = tid; x < 1600; x += 1024) e2[x] = Eq[(size_t)l2[x / 100] * 100 + (x % 100)];
    }
    __syncthreads();
    if (act) {
      for (int x = tid; x < 1600; x += 1024) {
        int r = x / 100, j = x % 100;
        const int* lr = l3 + r * 4;
        float s = Ec[(size_t)lr[0] * 100 + j] + Ec[(size_t)lr[1] * 100 + j] +
                  Ec[(size_t)lr[2] * 100 + j] + Ec[(size_t)lr[3] * 100 + j];
        m3[x] = e2[x] + 0.25f * s;
      }
      for (int x = tid; x < 100; x += 1024)
        sum1[x] = e0[x] + 0.25f * (e1[x] + e1[100 + x] + e1[200 + x] + e1[300 + x]);
      for (int x = tid; x < 400; x += 1024) {
        int k = x / 100, j = x % 100;
        const float* e2k = e2 + k * 400;
        sum4[x] = e1[x] + 0.25f * (e2k[j] + e2k[100 + j] + e2k[200 + j] + e2k[300 + j]);
      }
    }
    __syncthreads();
    if (act) {
      for (int o = tid; o < 2100; o += 1024) {
        const float* in;
        const u32* W2;
        float bia;
        float* dst;
        int i = o % 100;
        if (o < 100)      { in = sum1;                           W2 = wagg2;          bia = baggf[i];       dst = ne0 + o; }
        else if (o < 500) { in = sum4 + ((o - 100) / 100) * 100; W2 = wagg2 + 5000;   bia = baggf[100 + i]; dst = ne1 + (o - 100); }
        else              { in = m3 + ((o - 500) / 100) * 100;   W2 = wagg2 + 10000;  bia = baggf[200 + i]; dst = ne2 + (o - 500); }
        float acc = bia;
        for (int j2 = 0; j2 < 50; j2++) {
          u32 w = W2[j2 * 100 + i];
          float2 iv = *(const float2*)(in + 2 * j2);
          acc = fmaf(bflo(w), iv.x, fmaf(bfhi(w), iv.y, acc));
        }
        *dst = tanhf(acc);
      }
    }
    __syncthreads();
    if (act) {
      for (int x = tid; x < 100; x += 1024)
        sum1[x] = ne0[x] + 0.25f * (ne1[x] + ne1[100 + x] + ne1[200 + x] + ne1[300 + x]);
      for (int x = tid; x < 400; x += 1024) {
        int k = x / 100, j = x % 100;
        const float* n2k = ne2 + k * 400;
        sum4[x] = ne1[x] + 0.25f * (n2k[j] + n2k[100 + j] + n2k[200 + j] + n2k[300 + j]);
      }
    }
    __syncthreads();
    if (act) {
      for (int o = tid; o < 500; o += 1024) {
        int i = o % 100;
        if (o < 100) {
          float acc = baggf[i];
          for (int j2 = 0; j2 < 50; j2++) {
            u32 w = wagg2[j2 * 100 + i];
            float2 iv = *(const float2*)(sum1 + 2 * j2);
            acc = fmaf(bflo(w), iv.x, fmaf(bfhi(w), iv.y, acc));
          }
          e0[i] = tanhf(acc);
        } else {
          const float* in = sum4 + ((o - 100) / 100) * 100;
          float acc = baggf[100 + i];
          for (int j2 = 0; j2 < 50; j2++) {
            u32 w = wagg2[5000 + j2 * 100 + i];
            float2 iv = *(const float2*)(in + 2 * j2);
            acc = fmaf(bflo(w), iv.x, fmaf(bfhi(w), iv.y, acc));
          }
          e1[o - 100] = tanhf(acc);
        }
      }
    }
    __syncthreads();
    if (act) {
      for (int x = tid; x < 100; x += 1024)
        sum1[x] = e0[x] + 0.25f * (e1[x] + e1[100 + x] + e1[200 + x] + e1[300 + x]);
    }
    __syncthreads();
    if (act) {
      for (int o = tid; o < 100; o += 1024) {
        float acc = baggf[o];
        for (int j2 = 0; j2 < 50; j2++) {
          u32 w = wagg2[j2 * 100 + o];
          float2 iv = *(const float2*)(sum1 + 2 * j2);
          acc = fmaf(bflo(w), iv.x, fmaf(bfhi(w), iv.y, acc));
        }
        ne0[o] = tanhf(acc);
      }
    }
    __syncthreads();
    if (act) {
      for (int o = tid; o < 100; o += 1024) {
        float acc = blastf[o];
        for (int j2 = 0; j2 < 50; j2++) {
          u32 w = wlast2[j2 * 100 + o];
          float2 iv = *(const float2*)(ne0 + 2 * j2);
          acc = fmaf(bflo(w), iv.x, fmaf(bfhi(w), iv.y, acc));
        }
        emq[o] = tanhf(acc);
      }
    } else {
      for (int x = tid; x < 100; x += 1024) emq[x] = Eq[(size_t)qt * 100 + x];
    }
    __syncthreads();
    for (int o = tid; o < 300; o += 1024) {
      float acc = erw[rt * 300 + o];
      for (int j2 = 0; j2 < 50; j2++) {
        u32 w = wih1a2[j2 * 300 + o];
        float2 ev = *(const float2*)(emq + 2 * j2);
        acc = fmaf(bflo(w), ev.x, fmaf(bfhi(w), ev.y, acc));
      }
      gi1_all[bt * 300 + o] = acc;
    }

    // ---- phaseB part ----
    const int qn = question[b * S_ + t + 1];
    if (tid < 4) { ci[tid] = cidx[qn * KC_ + tid]; cm[tid] = cmask[qn * KC_ + tid]; }
    __syncthreads();
    for (int u = tid; u < 500; u += 1024) {
      int row = u / 100, j = u % 100;
      float v;
      if (row == 0) v = Eq[(size_t)qn * 100 + j];
      else {
        int k = row - 1;
        v = cm[k] ? Ec[(size_t)ci[k] * 100 + j] : 0.f;
      }
      qcf[u] = v;
    }
    __syncthreads();
    for (int o = tid; o < 500; o += 1024) {
      int q = o / 100, i = o % 100;
      float acc = b_key[i];
      const float* src = qcf + q * 100;
      for (int j = 0; j < 100; j++) acc += src[j] * wkeyT[j * 100 + i];
      qtl[o] = tanhf(acc);
    }
    __syncthreads();
    if (tid < 20) {
      int q = tid / 4, part = tid % 4;
      float acc = 0.f;
      for (int j = part * 25; j < part * 25 + 25; j++) acc += qtl[q * 100 + j] * W_W[j];
      qwp[tid] = acc;
    }
    __syncthreads();
    if (tid < 5) qw_all[bt * 5 + tid] = qwp[tid * 4] + qwp[tid * 4 + 1] + qwp[tid * 4 + 2] + qwp[tid * 4 + 3];

    if (t > RK_ && tid < 64) {
      const int s0 = tid, s1 = tid + 64;
      float v0 = -__builtin_inff(), v1 = -__builtin_inff();
      if (s0 < t) {
        int qs = question[b * S_ + s0];
        float a = 0.f;
        for (int j = 0; j < 100; j++) a += Eq[(size_t)qs * 100 + j] * qcf[j];
        v0 = a;
      }
      if (s1 < t) {
        int qs = question[b * S_ + s1];
        float a = 0.f;
        for (int j = 0; j < 100; j++) a += Eq[(size_t)qs * 100 + j] * qcf[j];
        v1 = a;
      }
      for (int pass = 0; pass < 10; pass++) {
        float bv; int bi;
        if (v1 > v0) { bv = v1; bi = s1; } else { bv = v0; bi = s0; }
#pragma unroll
        for (int off = 1; off < 64; off <<= 1) {
          float ov = __shfl_xor(bv, off);
          int oi = __shfl_xor(bi, off);
          if (ov > bv || (ov == bv && oi < bi)) { bv = ov; bi = oi; }
        }
        if (tid == 0) top10_all[bt * 10 + pass] = bi;
        if (bi == s0) v0 = -__builtin_inff();
        else if (bi == s1) v1 = -__builtin_inff();
      }
    }
    __syncthreads();  // drain all global stores (vmcnt(0) before barrier)
    if (tid == 0) __hip_atomic_store(&flags[bt], MAGIC, __ATOMIC_RELEASE, __HIP_MEMORY_SCOPE_AGENT);
    return;
  }

  // ===================== CONSUMER: sequential scan (R13 body) ==============
  const int b = blockIdx.x;
  const int grp = tid >> 2, sub = tid & 3;
  const int ptid = tid - 424;
  const uint4* wimg = (const uint4*)wcat16;
  int* bflags = flags + (size_t)b * T_;

  float* g2hist = S;             // 12700
  float* hcomb  = S + 12700;     // 200
  float* h1n    = S + 12900;     // 100
  float* g2v    = S + 13000;     // 100
  float* gh2    = S + 13100;     // 300
  float* kqs    = S + 13400;     // 100
  float* gi1d   = S + 13500;     // [2][300]
  float* qcd    = S + 14100;     // [2][500]
  float* qwd    = S + 15100;     // [2][8]
  float* bresS  = S + 15120;     // 1792
  float* wkS    = S + 16912;     // 100
  float* ogs    = S + 17012;     // [2][56]
  float* kwhist = S + 17124;     // 128
  int*   icons  = (int*)(S + 17252);
  int*   topd   = icons;         // [2][10]
  int*   cidS   = icons + 20;    // 8
  int*   cid0S  = icons + 28;    // 8
  // icons[36] = qn1S, icons[37] = qnS

  if (tid == 0) { spinflag(&bflags[0]); spinflag(&bflags[1]); }
  __syncthreads();

  for (int x = tid; x < 1792; x += 1024) bresS[x] = bcat[x];
  if (tid < 100) wkS[tid] = W_W[100 + tid];

  const float bWv = b_W[0];
  const float kw0 = scal[0];

  if (tid < 100) {
    hcomb[tid] = h1_init[b * 100 + tid];
    g2hist[tid] = 0.f;
  } else if (tid < 200) {
    hcomb[tid] = h2_init[b * 100 + (tid - 100)];
  }
  if (tid < 128) kwhist[tid] = kw0;
  if (tid < 300) gi1d[tid] = gi1_all[(size_t)b * T_ * 300 + tid];
  if (tid >= 300 && tid < 305) qwd[tid - 300] = qw_all[(size_t)b * T_ * 5 + (tid - 300)];
  if (tid == 306) { icons[36] = question[b * S_ + 2]; icons[37] = question[b * S_ + 3]; }
  if (tid >= 320 && tid < 328) {
    int k = tid - 320, qn0 = question[b * S_ + 1];
    cid0S[k] = (k < 4) ? cidx[qn0 * KC_ + k] : cmask[qn0 * KC_ + k - 4];
  }
  if (tid >= 328 && tid < 336) {
    int k = tid - 328, qn1 = question[b * S_ + 2];
    cidS[k] = (k < 4) ? cidx[qn1 * KC_ + k] : cmask[qn1 * KC_ + k - 4];
  }
  __syncthreads();
  if (tid < 500) {
    int q = tid / 100, j = tid % 100;
    int qn0 = question[b * S_ + 1];
    qcd[tid] = (q == 0) ? Eq[(size_t)qn0 * 100 + j]
                        : (cid0S[4 + q - 1] ? Ec[(size_t)cid0S[q - 1] * 100 + j] : 0.f);
  }
  __syncthreads();

  for (int t = 0; t < T_; ++t) {
    const size_t bt = (size_t)b * T_ + t;
    const int cur = t & 1, nxt = cur ^ 1;
    const bool pf = (t + 1) < T_;
    const int qn1 = icons[36], qn2 = icons[37];

    float pqc = 0.f, pgi = 0.f, pqw = 0.f;
    int ptop = 0, pci = 0, pqn = 0;
    if (pf) {
      if (ptid >= 0 && ptid < 500) {
        int q = ptid / 100, j = ptid % 100;
        pqc = (q == 0) ? Eq[(size_t)qn1 * 100 + j]
                       : (cidS[4 + q - 1] ? Ec[(size_t)cidS[q - 1] * 100 + j] : 0.f);
      }
      if (ptid >= 0 && ptid < 300) pgi = gi1_all[(bt + 1) * 300 + ptid];
      if (tid >= 924 && tid < 929) pqw = qw_all[(bt + 1) * 5 + (tid - 924)];
      if (tid >= 929 && tid < 939 && (t + 1) > RK_) ptop = top10_all[(bt + 1) * 10 + (tid - 929)];
      if (tid >= 939 && tid < 947 && (t + 2) < T_) {
        int k = tid - 939;
        pci = (k < 4) ? cidx[qn2 * KC_ + k] : cmask[qn2 * KC_ + k - 4];
      }
      if (tid == 947) pqn = question[b * S_ + min(t + 4, S_ - 1)];
    }

    // ---- S1: fused gh1+GRU1 | gh2 | og s>=1 ----
    if (grp < 200) {
      const bool g1 = (grp < 100);
      const int j = g1 ? grp : (grp - 100);
      const int s0 = g1 ? j : (300 + j);
      uint4 w0[4], w1[4], w2[4];
      {
        const uint4* p0 = wimg + (size_t)s0 * 16 + sub * 4;
        const uint4* p1 = wimg + (size_t)(s0 + 100) * 16 + sub * 4;
        const uint4* p2 = wimg + (size_t)(s0 + 200) * 16 + sub * 4;
#pragma unroll
        for (int c = 0; c < 4; ++c) { w0[c] = p0[c]; w1[c] = p1[c]; w2[c] = p2[c]; }
      }
      float hr[32];
#pragma unroll
      for (int c = 25; c < 32; ++c) hr[c] = 0.f;
      const int off = g1 ? 0 : 100;
#pragma unroll
      for (int c = 0; c < 25; ++c) hr[c] = hcomb[off + sub * 25 + c];
      float a0 = bf16_dot32(w0, hr);
      float a1 = bf16_dot32(w1, hr);
      float a2 = bf16_dot32(w2, hr);
      a0 += __shfl_xor(a0, 1); a0 += __shfl_xor(a0, 2);
      a1 += __shfl_xor(a1, 1); a1 += __shfl_xor(a1, 2);
      a2 += __shfl_xor(a2, 1); a2 += __shfl_xor(a2, 2);
      if (sub == 0) {
        if (g1) {
          float g0 = a0 + bresS[j], gg1 = a1 + bresS[100 + j], gg2 = a2 + bresS[200 + j];
          float rg = sigmf(gi1d[cur * 300 + j] + g0);
          float z  = sigmf(gi1d[cur * 300 + 100 + j] + gg1);
          float n  = tanhf(gi1d[cur * 300 + 200 + j] + rg * gg2);
          h1n[j] = (1.f - z) * n + z * hcomb[j];
        } else {
          gh2[j]       = a0 + bresS[300 + j];
          gh2[100 + j] = a1 + bresS[400 + j];
          gh2[200 + j] = a2 + bresS[500 + j];
        }
      }
    } else if (grp < 250) {
      int d = grp - 200;
      int s = 1 + d / 5, q = d % 5;
      bool valid = (t > RK_) || (s - 1 < t);
      float a = 0.f;
      if (valid) {
        int idx = (t > RK_) ? topd[cur * 10 + s - 1] : (s - 1);
        const float* qcr = &qcd[cur * 500 + q * 100 + sub * 25];
        const float* hrow = &g2hist[idx * 100 + sub * 25];
#pragma unroll
        for (int c = 0; c < 25; ++c) a = fmaf(qcr[c], hrow[c], a);
      }
      a += __shfl_xor(a, 1);
      a += __shfl_xor(a, 2);
      if (sub == 0) ogs[cur * 56 + s * 5 + q] = a;
    }
    __syncthreads();  // b1

    // ---- S3: fused gi2+GRU2 -> g2v | h1 copy ----
    if (grp < 100) {
      const int j = grp;
      uint4 w0[4], w1[4], w2[4];
      {
        const uint4* p0 = wimg + (size_t)(1024 + j) * 16 + sub * 4;
        const uint4* p1 = wimg + (size_t)(1124 + j) * 16 + sub * 4;
        const uint4* p2 = wimg + (size_t)(1224 + j) * 16 + sub * 4;
#pragma unroll
        for (int c = 0; c < 4; ++c) { w0[c] = p0[c]; w1[c] = p1[c]; w2[c] = p2[c]; }
      }
      float hr[32];
#pragma unroll
      for (int c = 25; c < 32; ++c) hr[c] = 0.f;
#pragma unroll
      for (int c = 0; c < 25; ++c) hr[c] = h1n[sub * 25 + c];
      float a0 = bf16_dot32(w0, hr);
      float a1 = bf16_dot32(w1, hr);
      float a2 = bf16_dot32(w2, hr);
      a0 += __shfl_xor(a0, 1); a0 += __shfl_xor(a0, 2);
      a1 += __shfl_xor(a1, 1); a1 += __shfl_xor(a1, 2);
      a2 += __shfl_xor(a2, 1); a2 += __shfl_xor(a2, 2);
      if (sub == 0) {
        float i_r = a0 + bresS[1024 + j], i_z = a1 + bresS[1124 + j], i_n = a2 + bresS[1224 + j];
        float rg = sigmf(i_r + gh2[j]);
        float z  = sigmf(i_z + gh2[100 + j]);
        float n  = tanhf(i_n + rg * gh2[200 + j]);
        g2v[j] = (1.f - z) * n + z * hcomb[100 + j];
      }
    } else if (tid >= 400 && tid < 500) {
      hcomb[tid - 400] = h1n[tid - 400];
    }
    __syncthreads();  // b2

    // ---- S5: kq | og s=0 | commits + h2/g2hist | flag poll for t+2 ----
    if (grp < 100) {
      float hr[32];
#pragma unroll
      for (int c = 25; c < 32; ++c) hr[c] = 0.f;
#pragma unroll
      for (int c = 0; c < 25; ++c) hr[c] = g2v[sub * 25 + c];
      uint4 wc[4];
      {
        const uint4* wp = wimg + (size_t)(1536 + grp) * 16 + sub * 4;
#pragma unroll
        for (int c = 0; c < 4; ++c) wc[c] = wp[c];
      }
      float a = bf16_dot32(wc, hr);
      a += __shfl_xor(a, 1);
      a += __shfl_xor(a, 2);
      if (sub == 0) kqs[grp] = tanhf(a + bresS[1536 + grp]) * wkS[grp];
    } else if (grp < 105) {
      int q = grp - 100;
      const float* qcr = &qcd[cur * 500 + q * 100 + sub * 25];
      float a = 0.f;
#pragma unroll
      for (int c = 0; c < 25; ++c) a = fmaf(qcr[c], g2v[sub * 25 + c], a);
      a += __shfl_xor(a, 1);
      a += __shfl_xor(a, 2);
      if (sub == 0) ogs[cur * 56 + q] = a;
    }
    if (ptid >= 0) {
      if (pf) {
        if (ptid < 500) qcd[nxt * 500 + ptid] = pqc;
        if (ptid < 300) gi1d[nxt * 300 + ptid] = pgi;
        if (tid >= 924 && tid < 929) qwd[nxt * 8 + tid - 924] = pqw;
        if (tid >= 929 && tid < 939 && (t + 1) > RK_) topd[nxt * 10 + tid - 929] = min(T_ - 1, max(0, ptop));
        if (tid >= 939 && tid < 947 && (t + 2) < T_) cidS[tid - 939] = pci;
        if (tid == 947) { icons[36] = qn2; icons[37] = pqn; }
      }
      if (tid == 948 && (t + 2) < T_) spinflag(&bflags[t + 2]);
      if (t > 0 && ptid < 100) {
        hcomb[100 + ptid] = g2v[ptid];
        g2hist[t * 100 + ptid] = g2v[ptid];
      }
    }
    __syncthreads();  // b3

    // ---- S6: wave-0 kw/softmax/store ----
    if (tid < 64) {
      float v = (tid < 50) ? (kqs[tid] + kqs[tid + 50]) : 0.f;
      v += __shfl_xor(v, 1);
      v += __shfl_xor(v, 2);
      v += __shfl_xor(v, 4);
      v += __shfl_xor(v, 8);
      v += __shfl_xor(v, 16);
      v += __shfl_xor(v, 32);
      const float kw = v;
      float pq = 0.f;
      if (tid < 5) {
        const float qw = qwd[cur * 8 + tid];
        float tmp[11];
        float m = -__builtin_inff();
#pragma unroll
        for (int s = 0; s < 11; ++s) {
          float kws;
          bool valid;
          if (s == 0) { kws = kw; valid = true; }
          else if (t > RK_) { kws = kwhist[topd[cur * 10 + s - 1]]; valid = true; }
          else { valid = (s - 1 < t); kws = kwhist[s - 1]; }
          float tv = valid ? (qw + kws + bWv) : NEGV;
          tmp[s] = tv;
          m = fmaxf(m, tv);
        }
        float den = 0.f, num = 0.f;
#pragma unroll
        for (int s = 0; s < 11; ++s) {
          float e = expf(tmp[s] - m);
          den += e;
          num += e * ogs[cur * 56 + s * 5 + tid];
        }
        pq = num / den;
      }
      if (tid == 5 && t > 0) kwhist[t] = kw;
      float sp = pq;
      sp += __shfl_xor(sp, 1);
      sp += __shfl_xor(sp, 2);
      sp += __shfl_xor(sp, 4);
      if (tid == 0) {
        int col = (t == 0) ? 0 : (t + 1);
        out[b * S_ + col] = sp;
        if (t == 0) out[b * S_ + 1] = 0.f;
      }
    }
  }
}

// ---------------------------------------------------------------------------
extern "C" void kernel_launch(void* const* d_in, const int* in_sizes, int n_in,
                              void* d_out, int out_size, void* d_ws, size_t ws_size,
                              hipStream_t stream)
{
  (void)in_sizes; (void)n_in; (void)out_size; (void)ws_size;
  const float* Eq     = (const float*)d_in[0];
  const float* Ec     = (const float*)d_in[1];
  const float* Er     = (const float*)d_in[2];
  const float* W_ih1  = (const float*)d_in[3];
  const float* W_hh1  = (const float*)d_in[4];
  const float* b_ih1  = (const float*)d_in[5];
  const float* b_hh1  = (const float*)d_in[6];
  const float* W_ih2  = (const float*)d_in[7];
  const float* W_hh2  = (const float*)d_in[8];
  const float* b_ih2  = (const float*)d_in[9];
  const float* b_hh2  = (const float*)d_in[10];
  const float* Wagg   = (const float*)d_in[11];
  const float* bagg   = (const float*)d_in[12];
  const float* W_last = (const float*)d_in[13];
  const float* b_last = (const float*)d_in[14];
  const float* W_query= (const float*)d_in[15];
  const float* b_query= (const float*)d_in[16];
  const float* W_key  = (const float*)d_in[17];
  const float* b_key  = (const float*)d_in[18];
  const float* W_W    = (const float*)d_in[19];
  const float* b_W    = (const float*)d_in[20];
  const float* h1_init= (const float*)d_in[21];
  const float* h2_init= (const float*)d_in[22];
  const int* question = (const int*)d_in[23];
  const int* response = (const int*)d_in[24];
  const int* mask     = (const int*)d_in[25];
  const int* qnb      = (const int*)d_in[26];
  const int* snb      = (const int*)d_in[27];
  const int* cidx     = (const int*)d_in[28];
  const int* cmask    = (const int*)d_in[29];
  float* out = (float*)d_out;

  char* ws = (char*)d_ws;
  size_t off = 0;
  auto alloc = [&](size_t bytes) -> void* {
    void* p = ws + off;
    off += (bytes + 255) & ~(size_t)255;
    return p;
  };
  u32*   wih1a2 = (u32*)alloc(15000 * 4);
  float* erw    = (float*)alloc(600 * 4);
  u32*   wagg2  = (u32*)alloc(15000 * 4);
  u32*   wlast2 = (u32*)alloc(5000 * 4);
  float* wkeyT  = (float*)alloc(10000 * 4);
  float* scal   = (float*)alloc(4);
  u32*   wcat16 = (u32*)alloc(114688 * 4);
  float* bcat   = (float*)alloc(1792 * 4);
  float* gi1_all = (float*)alloc((size_t)B_ * T_ * 300 * 4);
  float* qw_all  = (float*)alloc((size_t)B_ * T_ * 5 * 4);
  int*   top10   = (int*)alloc((size_t)B_ * T_ * 10 * 4);
  int*   flags   = (int*)alloc((size_t)B_ * T_ * 4);

  hipLaunchKernelGGL(setupk, dim3(128), dim3(256), 0, stream,
      Er, W_ih1, b_ih1, Wagg, W_last, W_key, b_query, W_W, W_query,
      W_hh1, W_hh2, W_ih2, b_hh1, b_hh2, b_ih2,
      wih1a2, erw, wagg2, wlast2, wkeyT, scal, wcat16, bcat);

  hipLaunchKernelGGL(megak, dim3(B_ + B_ * T_), dim3(1024), 0, stream,
      wcat16, bcat, wih1a2, erw, wagg2, wlast2, wkeyT,
      gi1_all, qw_all, top10, flags,
      W_W, b_W, b_key, bagg, b_last,
      Eq, Ec, question, response, mask, qnb, snb, cidx, cmask,
      h1_init, h2_init, scal, out);
}

// Round 16
// 3259.945 us; speedup vs baseline: 1.7812x; 1.7812x over previous
//
#include <hip/hip_runtime.h>
#include <hip/hip_bf16.h>
#include <math.h>

typedef unsigned int u32;

#define B_ 128
#define S_ 128
#define T_ 127
#define D_ 100
#define QN_ 4
#define SN_ 4
#define KC_ 4
#define RK_ 10
#define NEGV -1000000000.0f
#define MAGIC 0x05EAF00D

__device__ __forceinline__ float sigmf(float x) { return 1.0f / (1.0f + expf(-x)); }

__device__ __forceinline__ u32 f2bfbits(float x) {
  __hip_bfloat16 h = __float2bfloat16(x);
  unsigned short s;
  __builtin_memcpy(&s, &h, 2);
  return (u32)s;
}
__device__ __forceinline__ float bflo(u32 w) { return __uint_as_float(w << 16); }
__device__ __forceinline__ float bfhi(u32 w) { return __uint_as_float(w & 0xffff0000u); }

// R16: sleep-backoff poll — the R15 tight spin saturated L2 with agent-scope
// acquires from 128 consumer blocks and throttled the producers ~9x.
__device__ __forceinline__ void spinflag(int* f) {
  int sp = 0;
  while (__hip_atomic_load(f, __ATOMIC_ACQUIRE, __HIP_MEMORY_SCOPE_AGENT) != MAGIC && sp < (1 << 16)) {
    __builtin_amdgcn_s_sleep(32);
    ++sp;
  }
}

// ---------------------------------------------------------------------------
// Setup (unchanged from R15).
// ---------------------------------------------------------------------------
__global__ __launch_bounds__(256) void setupk(
    const float* Er, const float* W_ih1, const float* b_ih1,
    const float* Wagg, const float* W_last, const float* W_key,
    const float* b_query, const float* W_W, const float* W_query,
    const float* W_hh1, const float* W_hh2, const float* W_ih2,
    const float* b_hh1, const float* b_hh2, const float* b_ih2,
    u32* wih1a2, float* erw, u32* wagg2, u32* wlast2, float* wkeyT,
    float* scal, u32* wcat16, float* bcat)
{
  int gid = blockIdx.x * blockDim.x + threadIdx.x;
  int gsz = gridDim.x * blockDim.x;

  for (int x = gid; x < 15000; x += gsz) {
    int j2 = x / 300, o = x % 300;
    wih1a2[x] = (f2bfbits(W_ih1[o * 200 + 2 * j2 + 1]) << 16) | f2bfbits(W_ih1[o * 200 + 2 * j2]);
  }
  for (int x = gid; x < 600; x += gsz) {
    int r = x / 300, i = x % 300;
    float acc = b_ih1[i];
    for (int j = 0; j < 100; j++) acc += Er[r * 100 + j] * W_ih1[i * 200 + 100 + j];
    erw[x] = acc;
  }
  for (int x = gid; x < 15000; x += gsz) {
    int h = x / 5000, r = x % 5000, j2 = r / 100, i = r % 100;
    wagg2[x] = (f2bfbits(Wagg[h * 10000 + i * 100 + 2 * j2 + 1]) << 16)
             | f2bfbits(Wagg[h * 10000 + i * 100 + 2 * j2]);
  }
  for (int x = gid; x < 5000; x += gsz) {
    int j2 = x / 100, i = x % 100;
    wlast2[x] = (f2bfbits(W_last[i * 100 + 2 * j2 + 1]) << 16) | f2bfbits(W_last[i * 100 + 2 * j2]);
  }
  for (int x = gid; x < 10000; x += gsz) {
    int j = x / 100, i = x % 100;
    wkeyT[j * 100 + i] = W_key[i * 100 + j];
  }
  for (int x = gid; x < 114688; x += gsz) {
    int slot = x / 64, rem = x % 64, sbu = rem / 16, k = rem % 16;
    const float* src = nullptr;
    if (slot < 300)                       src = W_hh1 + (size_t)slot * 100;
    else if (slot < 600)                  src = W_hh2 + (size_t)(slot - 300) * 100;
    else if (slot >= 1024 && slot < 1324) src = W_ih2 + (size_t)(slot - 1024) * 100;
    else if (slot >= 1536 && slot < 1636) src = W_query + (size_t)(slot - 1536) * 100;
    u32 lo = 0, hi = 0;
    if (src) {
      int e0 = 2 * k, e1 = 2 * k + 1;
      if (e0 < 25) lo = f2bfbits(src[sbu * 25 + e0]);
      if (e1 < 25) hi = f2bfbits(src[sbu * 25 + e1]);
    }
    wcat16[x] = (hi << 16) | lo;
  }
  for (int x = gid; x < 1792; x += gsz) {
    float v = 0.f;
    if (x < 300) v = b_hh1[x];
    else if (x < 600) v = b_hh2[x - 300];
    else if (x >= 1024 && x < 1324) v = b_ih2[x - 1024];
    else if (x >= 1536 && x < 1636) v = b_query[x - 1536];
    bcat[x] = v;
  }
  if (gid == 0) {
    float acc = 0.f;
    for (int i = 0; i < 100; i++) acc += tanhf(b_query[i]) * W_W[100 + i];
    scal[0] = acc;
  }
}

// bf16 row-dot helper: dot(unpack(w[0..3]), hr[0..31])
__device__ __forceinline__ float bf16_dot32(const uint4 w[4], const float hr[32]) {
  float a = 0.f;
#pragma unroll
  for (int c = 0; c < 4; ++c) {
    uint4 ww = w[c];
    const int e = c * 8;
    a = fmaf(__uint_as_float(ww.x << 16),         hr[e + 0], a);
    a = fmaf(__uint_as_float(ww.x & 0xffff0000u), hr[e + 1], a);
    a = fmaf(__uint_as_float(ww.y << 16),         hr[e + 2], a);
    a = fmaf(__uint_as_float(ww.y & 0xffff0000u), hr[e + 3], a);
    a = fmaf(__uint_as_float(ww.z << 16),         hr[e + 4], a);
    a = fmaf(__uint_as_float(ww.z & 0xffff0000u), hr[e + 5], a);
    a = fmaf(__uint_as_float(ww.w << 16),         hr[e + 6], a);
    a = fmaf(__uint_as_float(ww.w & 0xffff0000u), hr[e + 7], a);
  }
  return a;
}

// ---------------------------------------------------------------------------
// MEGA kernel (R15 structure, R16 spin fix): blocks [0,128) = consumers,
// blocks [128,16384) = producers (phaseA+phaseB per (b,t), t-major).
// ---------------------------------------------------------------------------
__global__ __launch_bounds__(1024) void megak(
    const u32* wcat16, const float* bcat,
    const u32* wih1a2, const float* erw, const u32* wagg2, const u32* wlast2,
    const float* wkeyT,
    float* gi1_all, float* qw_all, int* top10_all, int* flags,
    const float* W_W, const float* b_W, const float* b_key, const float* baggf, const float* blastf,
    const float* Eq, const float* Ec, const int* question, const int* response, const int* mask,
    const int* qnb, const int* snb, const int* cidx, const int* cmask,
    const float* h1_init, const float* h2_init, const float* scal,
    float* out)
{
  __shared__ __align__(16) float SMEM[17600];
  const int tid = threadIdx.x;
  float* S = SMEM;

  if (blockIdx.x >= B_) {
    // =================== PRODUCER: phaseA + phaseB for one (b,t) ===========
    const int p = blockIdx.x - B_;
    const int t = p / B_, b = p % B_;
    const size_t bt = (size_t)b * T_ + t;

    float* e0 = S;        float* ne0 = S + 100;  float* e1 = S + 200;  float* ne1 = S + 600;
    float* e2 = S + 1000; float* ne2 = S + 2600; float* m3 = S + 4200;
    float* sum4 = S + 5800; float* sum1 = S + 6200; float* emq = S + 6300;
    float* qcf = S + 6400; float* qtl = S + 6900; float* qwp = S + 7400;
    int* ip = (int*)(S + 7424);
    int* l1 = ip; int* l2 = ip + 4; int* l3 = ip + 20; int* ci = ip + 84; int* cm = ip + 88;

    const int qt = question[b * S_ + t];
    const int mt = mask[b * S_ + t];
    const int rt = response[b * S_ + t];
    const bool act = (mt != 0);

    if (act) {
      if (tid < 4) l1[tid] = qnb[qt * QN_ + tid];
      for (int x = tid; x < 100; x += 1024) e0[x] = Eq[(size_t)qt * 100 + x];
    }
    __syncthreads();
    if (act) {
      if (tid < 16) l2[tid] = snb[l1[tid >> 2] * SN_ + (tid & 3)];
      for (int x = tid; x < 400; x += 1024) e1[x] = Ec[(size_t)l1[x / 100] * 100 + (x % 100)];
    }
    __syncthreads();
    if (act) {
      if (tid < 64) l3[tid] = qnb[l2[tid >> 2] * QN_ + (tid & 3)];
      for (int x = tid; x < 1600; x += 1024) e2[x] = Eq[(size_t)l2[x / 100] * 100 + (x % 100)];
    }
    __syncthreads();
    if (act) {
      for (int x = tid; x < 1600; x += 1024) {
        int r = x / 100, j = x % 100;
        const int* lr = l3 + r * 4;
        float s = Ec[(size_t)lr[0] * 100 + j] + Ec[(size_t)lr[1] * 100 + j] +
                  Ec[(size_t)lr[2] * 100 + j] + Ec[(size_t)lr[3] * 100 + j];
        m3[x] = e2[x] + 0.25f * s;
      }
      for (int x = tid; x < 100; x += 1024)
        sum1[x] = e0[x] + 0.25f * (e1[x] + e1[100 + x] + e1[200 + x] + e1[300 + x]);
      for (int x = tid; x < 400; x += 1024) {
        int k = x / 100, j = x % 100;
        const float* e2k = e2 + k * 400;
        sum4[x] = e1[x] + 0.25f * (e2k[j] + e2k[100 + j] + e2k[200 + j] + e2k[300 + j]);
      }
    }
    __syncthreads();
    if (act) {
      for (int o = tid; o < 2100; o += 1024) {
        const float* in;
        const u32* W2;
        float bia;
        float* dst;
        int i = o % 100;
        if (o < 100)      { in = sum1;                           W2 = wagg2;          bia = baggf[i];       dst = ne0 + o; }
        else if (o < 500) { in = sum4 + ((o - 100) / 100) * 100; W2 = wagg2 + 5000;   bia = baggf[100 + i]; dst = ne1 + (o - 100); }
        else              { in = m3 + ((o - 500) / 100) * 100;   W2 = wagg2 + 10000;  bia = baggf[200 + i]; dst = ne2 + (o - 500); }
        float acc = bia;
        for (int j2 = 0; j2 < 50; j2++) {
          u32 w = W2[j2 * 100 + i];
          float2 iv = *(const float2*)(in + 2 * j2);
          acc = fmaf(bflo(w), iv.x, fmaf(bfhi(w), iv.y, acc));
        }
        *dst = tanhf(acc);
      }
    }
    __syncthreads();
    if (act) {
      for (int x = tid; x < 100; x += 1024)
        sum1[x] = ne0[x] + 0.25f * (ne1[x] + ne1[100 + x] + ne1[200 + x] + ne1[300 + x]);
      for (int x = tid; x < 400; x += 1024) {
        int k = x / 100, j = x % 100;
        const float* n2k = ne2 + k * 400;
        sum4[x] = ne1[x] + 0.25f * (n2k[j] + n2k[100 + j] + n2k[200 + j] + n2k[300 + j]);
      }
    }
    __syncthreads();
    if (act) {
      for (int o = tid; o < 500; o += 1024) {
        int i = o % 100;
        if (o < 100) {
          float acc = baggf[i];
          for (int j2 = 0; j2 < 50; j2++) {
            u32 w = wagg2[j2 * 100 + i];
            float2 iv = *(const float2*)(sum1 + 2 * j2);
            acc = fmaf(bflo(w), iv.x, fmaf(bfhi(w), iv.y, acc));
          }
          e0[i] = tanhf(acc);
        } else {
          const float* in = sum4 + ((o - 100) / 100) * 100;
          float acc = baggf[100 + i];
          for (int j2 = 0; j2 < 50; j2++) {
            u32 w = wagg2[5000 + j2 * 100 + i];
            float2 iv = *(const float2*)(in + 2 * j2);
            acc = fmaf(bflo(w), iv.x, fmaf(bfhi(w), iv.y, acc));
          }
          e1[o - 100] = tanhf(acc);
        }
      }
    }
    __syncthreads();
    if (act) {
      for (int x = tid; x < 100; x += 1024)
        sum1[x] = e0[x] + 0.25f * (e1[x] + e1[100 + x] + e1[200 + x] + e1[300 + x]);
    }
    __syncthreads();
    if (act) {
      for (int o = tid; o < 100; o += 1024) {
        float acc = baggf[o];
        for (int j2 = 0; j2 < 50; j2++) {
          u32 w = wagg2[j2 * 100 + o];
          float2 iv = *(const float2*)(sum1 + 2 * j2);
          acc = fmaf(bflo(w), iv.x, fmaf(bfhi(w), iv.y, acc));
        }
        ne0[o] = tanhf(acc);
      }
    }
    __syncthreads();
    if (act) {
      for (int o = tid; o < 100; o += 1024) {
        float acc = blastf[o];
        for (int j2 = 0; j2 < 50; j2++) {
          u32 w = wlast2[j2 * 100 + o];
          float2 iv = *(const float2*)(ne0 + 2 * j2);
          acc = fmaf(bflo(w), iv.x, fmaf(bfhi(w), iv.y, acc));
        }
        emq[o] = tanhf(acc);
      }
    } else {
      for (int x = tid; x < 100; x += 1024) emq[x] = Eq[(size_t)qt * 100 + x];
    }
    __syncthreads();
    for (int o = tid; o < 300; o += 1024) {
      float acc = erw[rt * 300 + o];
      for (int j2 = 0; j2 < 50; j2++) {
        u32 w = wih1a2[j2 * 300 + o];
        float2 ev = *(const float2*)(emq + 2 * j2);
        acc = fmaf(bflo(w), ev.x, fmaf(bfhi(w), ev.y, acc));
      }
      gi1_all[bt * 300 + o] = acc;
    }

    // ---- phaseB part ----
    const int qn = question[b * S_ + t + 1];
    if (tid < 4) { ci[tid] = cidx[qn * KC_ + tid]; cm[tid] = cmask[qn * KC_ + tid]; }
    __syncthreads();
    for (int u = tid; u < 500; u += 1024) {
      int row = u / 100, j = u % 100;
      float v;
      if (row == 0) v = Eq[(size_t)qn * 100 + j];
      else {
        int k = row - 1;
        v = cm[k] ? Ec[(size_t)ci[k] * 100 + j] : 0.f;
      }
      qcf[u] = v;
    }
    __syncthreads();
    for (int o = tid; o < 500; o += 1024) {
      int q = o / 100, i = o % 100;
      float acc = b_key[i];
      const float* src = qcf + q * 100;
      for (int j = 0; j < 100; j++) acc += src[j] * wkeyT[j * 100 + i];
      qtl[o] = tanhf(acc);
    }
    __syncthreads();
    if (tid < 20) {
      int q = tid / 4, part = tid % 4;
      float acc = 0.f;
      for (int j = part * 25; j < part * 25 + 25; j++) acc += qtl[q * 100 + j] * W_W[j];
      qwp[tid] = acc;
    }
    __syncthreads();
    if (tid < 5) qw_all[bt * 5 + tid] = qwp[tid * 4] + qwp[tid * 4 + 1] + qwp[tid * 4 + 2] + qwp[tid * 4 + 3];

    if (t > RK_ && tid < 64) {
      const int s0 = tid, s1 = tid + 64;
      float v0 = -__builtin_inff(), v1 = -__builtin_inff();
      if (s0 < t) {
        int qs = question[b * S_ + s0];
        float a = 0.f;
        for (int j = 0; j < 100; j++) a += Eq[(size_t)qs * 100 + j] * qcf[j];
        v0 = a;
      }
      if (s1 < t) {
        int qs = question[b * S_ + s1];
        float a = 0.f;
        for (int j = 0; j < 100; j++) a += Eq[(size_t)qs * 100 + j] * qcf[j];
        v1 = a;
      }
      for (int pass = 0; pass < 10; pass++) {
        float bv; int bi;
        if (v1 > v0) { bv = v1; bi = s1; } else { bv = v0; bi = s0; }
#pragma unroll
        for (int off = 1; off < 64; off <<= 1) {
          float ov = __shfl_xor(bv, off);
          int oi = __shfl_xor(bi, off);
          if (ov > bv || (ov == bv && oi < bi)) { bv = ov; bi = oi; }
        }
        if (tid == 0) top10_all[bt * 10 + pass] = bi;
        if (bi == s0) v0 = -__builtin_inff();
        else if (bi == s1) v1 = -__builtin_inff();
      }
    }
    __syncthreads();  // drain all global stores (vmcnt(0) before barrier)
    if (tid == 0) __hip_atomic_store(&flags[bt], MAGIC, __ATOMIC_RELEASE, __HIP_MEMORY_SCOPE_AGENT);
    return;
  }

  // ===================== CONSUMER: sequential scan (R13 body) ==============
  const int b = blockIdx.x;
  const int grp = tid >> 2, sub = tid & 3;
  const int ptid = tid - 424;
  const uint4* wimg = (const uint4*)wcat16;
  int* bflags = flags + (size_t)b * T_;

  float* g2hist = S;             // 12700
  float* hcomb  = S + 12700;     // 200
  float* h1n    = S + 12900;     // 100
  float* g2v    = S + 13000;     // 100
  float* gh2    = S + 13100;     // 300
  float* kqs    = S + 13400;     // 100
  float* gi1d   = S + 13500;     // [2][300]
  float* qcd    = S + 14100;     // [2][500]
  float* qwd    = S + 15100;     // [2][8]
  float* bresS  = S + 15120;     // 1792
  float* wkS    = S + 16912;     // 100
  float* ogs    = S + 17012;     // [2][56]
  float* kwhist = S + 17124;     // 128
  int*   icons  = (int*)(S + 17252);
  int*   topd   = icons;         // [2][10]
  int*   cidS   = icons + 20;    // 8
  int*   cid0S  = icons + 28;    // 8
  // icons[36] = qn1S, icons[37] = qnS

  if (tid == 0) { spinflag(&bflags[0]); spinflag(&bflags[1]); }
  __syncthreads();

  for (int x = tid; x < 1792; x += 1024) bresS[x] = bcat[x];
  if (tid < 100) wkS[tid] = W_W[100 + tid];

  const float bWv = b_W[0];
  const float kw0 = scal[0];

  if (tid < 100) {
    hcomb[tid] = h1_init[b * 100 + tid];
    g2hist[tid] = 0.f;
  } else if (tid < 200) {
    hcomb[tid] = h2_init[b * 100 + (tid - 100)];
  }
  if (tid < 128) kwhist[tid] = kw0;
  if (tid < 300) gi1d[tid] = gi1_all[(size_t)b * T_ * 300 + tid];
  if (tid >= 300 && tid < 305) qwd[tid - 300] = qw_all[(size_t)b * T_ * 5 + (tid - 300)];
  if (tid == 306) { icons[36] = question[b * S_ + 2]; icons[37] = question[b * S_ + 3]; }
  if (tid >= 320 && tid < 328) {
    int k = tid - 320, qn0 = question[b * S_ + 1];
    cid0S[k] = (k < 4) ? cidx[qn0 * KC_ + k] : cmask[qn0 * KC_ + k - 4];
  }
  if (tid >= 328 && tid < 336) {
    int k = tid - 328, qn1 = question[b * S_ + 2];
    cidS[k] = (k < 4) ? cidx[qn1 * KC_ + k] : cmask[qn1 * KC_ + k - 4];
  }
  __syncthreads();
  if (tid < 500) {
    int q = tid / 100, j = tid % 100;
    int qn0 = question[b * S_ + 1];
    qcd[tid] = (q == 0) ? Eq[(size_t)qn0 * 100 + j]
                        : (cid0S[4 + q - 1] ? Ec[(size_t)cid0S[q - 1] * 100 + j] : 0.f);
  }
  __syncthreads();

  for (int t = 0; t < T_; ++t) {
    const size_t bt = (size_t)b * T_ + t;
    const int cur = t & 1, nxt = cur ^ 1;
    const bool pf = (t + 1) < T_;
    const int qn1 = icons[36], qn2 = icons[37];

    float pqc = 0.f, pgi = 0.f, pqw = 0.f;
    int ptop = 0, pci = 0, pqn = 0;
    if (pf) {
      if (ptid >= 0 && ptid < 500) {
        int q = ptid / 100, j = ptid % 100;
        pqc = (q == 0) ? Eq[(size_t)qn1 * 100 + j]
                       : (cidS[4 + q - 1] ? Ec[(size_t)cidS[q - 1] * 100 + j] : 0.f);
      }
      if (ptid >= 0 && ptid < 300) pgi = gi1_all[(bt + 1) * 300 + ptid];
      if (tid >= 924 && tid < 929) pqw = qw_all[(bt + 1) * 5 + (tid - 924)];
      if (tid >= 929 && tid < 939 && (t + 1) > RK_) ptop = top10_all[(bt + 1) * 10 + (tid - 929)];
      if (tid >= 939 && tid < 947 && (t + 2) < T_) {
        int k = tid - 939;
        pci = (k < 4) ? cidx[qn2 * KC_ + k] : cmask[qn2 * KC_ + k - 4];
      }
      if (tid == 947) pqn = question[b * S_ + min(t + 4, S_ - 1)];
    }

    // ---- S1: fused gh1+GRU1 | gh2 | og s>=1 ----
    if (grp < 200) {
      const bool g1 = (grp < 100);
      const int j = g1 ? grp : (grp - 100);
      const int s0 = g1 ? j : (300 + j);
      uint4 w0[4], w1[4], w2[4];
      {
        const uint4* p0 = wimg + (size_t)s0 * 16 + sub * 4;
        const uint4* p1 = wimg + (size_t)(s0 + 100) * 16 + sub * 4;
        const uint4* p2 = wimg + (size_t)(s0 + 200) * 16 + sub * 4;
#pragma unroll
        for (int c = 0; c < 4; ++c) { w0[c] = p0[c]; w1[c] = p1[c]; w2[c] = p2[c]; }
      }
      float hr[32];
#pragma unroll
      for (int c = 25; c < 32; ++c) hr[c] = 0.f;
      const int off = g1 ? 0 : 100;
#pragma unroll
      for (int c = 0; c < 25; ++c) hr[c] = hcomb[off + sub * 25 + c];
      float a0 = bf16_dot32(w0, hr);
      float a1 = bf16_dot32(w1, hr);
      float a2 = bf16_dot32(w2, hr);
      a0 += __shfl_xor(a0, 1); a0 += __shfl_xor(a0, 2);
      a1 += __shfl_xor(a1, 1); a1 += __shfl_xor(a1, 2);
      a2 += __shfl_xor(a2, 1); a2 += __shfl_xor(a2, 2);
      if (sub == 0) {
        if (g1) {
          float g0 = a0 + bresS[j], gg1 = a1 + bresS[100 + j], gg2 = a2 + bresS[200 + j];
          float rg = sigmf(gi1d[cur * 300 + j] + g0);
          float z  = sigmf(gi1d[cur * 300 + 100 + j] + gg1);
          float n  = tanhf(gi1d[cur * 300 + 200 + j] + rg * gg2);
          h1n[j] = (1.f - z) * n + z * hcomb[j];
        } else {
          gh2[j]       = a0 + bresS[300 + j];
          gh2[100 + j] = a1 + bresS[400 + j];
          gh2[200 + j] = a2 + bresS[500 + j];
        }
      }
    } else if (grp < 250) {
      int d = grp - 200;
      int s = 1 + d / 5, q = d % 5;
      bool valid = (t > RK_) || (s - 1 < t);
      float a = 0.f;
      if (valid) {
        int idx = (t > RK_) ? topd[cur * 10 + s - 1] : (s - 1);
        const float* qcr = &qcd[cur * 500 + q * 100 + sub * 25];
        const float* hrow = &g2hist[idx * 100 + sub * 25];
#pragma unroll
        for (int c = 0; c < 25; ++c) a = fmaf(qcr[c], hrow[c], a);
      }
      a += __shfl_xor(a, 1);
      a += __shfl_xor(a, 2);
      if (sub == 0) ogs[cur * 56 + s * 5 + q] = a;
    }
    __syncthreads();  // b1

    // ---- S3: fused gi2+GRU2 -> g2v | h1 copy ----
    if (grp < 100) {
      const int j = grp;
      uint4 w0[4], w1[4], w2[4];
      {
        const uint4* p0 = wimg + (size_t)(1024 + j) * 16 + sub * 4;
        const uint4* p1 = wimg + (size_t)(1124 + j) * 16 + sub * 4;
        const uint4* p2 = wimg + (size_t)(1224 + j) * 16 + sub * 4;
#pragma unroll
        for (int c = 0; c < 4; ++c) { w0[c] = p0[c]; w1[c] = p1[c]; w2[c] = p2[c]; }
      }
      float hr[32];
#pragma unroll
      for (int c = 25; c < 32; ++c) hr[c] = 0.f;
#pragma unroll
      for (int c = 0; c < 25; ++c) hr[c] = h1n[sub * 25 + c];
      float a0 = bf16_dot32(w0, hr);
      float a1 = bf16_dot32(w1, hr);
      float a2 = bf16_dot32(w2, hr);
      a0 += __shfl_xor(a0, 1); a0 += __shfl_xor(a0, 2);
      a1 += __shfl_xor(a1, 1); a1 += __shfl_xor(a1, 2);
      a2 += __shfl_xor(a2, 1); a2 += __shfl_xor(a2, 2);
      if (sub == 0) {
        float i_r = a0 + bresS[1024 + j], i_z = a1 + bresS[1124 + j], i_n = a2 + bresS[1224 + j];
        float rg = sigmf(i_r + gh2[j]);
        float z  = sigmf(i_z + gh2[100 + j]);
        float n  = tanhf(i_n + rg * gh2[200 + j]);
        g2v[j] = (1.f - z) * n + z * hcomb[100 + j];
      }
    } else if (tid >= 400 && tid < 500) {
      hcomb[tid - 400] = h1n[tid - 400];
    }
    __syncthreads();  // b2

    // ---- S5: kq | og s=0 | commits + h2/g2hist | flag poll for t+2 ----
    if (grp < 100) {
      float hr[32];
#pragma unroll
      for (int c = 25; c < 32; ++c) hr[c] = 0.f;
#pragma unroll
      for (int c = 0; c < 25; ++c) hr[c] = g2v[sub * 25 + c];
      uint4 wc[4];
      {
        const uint4* wp = wimg + (size_t)(1536 + grp) * 16 + sub * 4;
#pragma unroll
        for (int c = 0; c < 4; ++c) wc[c] = wp[c];
      }
      float a = bf16_dot32(wc, hr);
      a += __shfl_xor(a, 1);
      a += __shfl_xor(a, 2);
      if (sub == 0) kqs[grp] = tanhf(a + bresS[1536 + grp]) * wkS[grp];
    } else if (grp < 105) {
      int q = grp - 100;
      const float* qcr = &qcd[cur * 500 + q * 100 + sub * 25];
      float a = 0.f;
#pragma unroll
      for (int c = 0; c < 25; ++c) a = fmaf(qcr[c], g2v[sub * 25 + c], a);
      a += __shfl_xor(a, 1);
      a += __shfl_xor(a, 2);
      if (sub == 0) ogs[cur * 56 + q] = a;
    }
    if (ptid >= 0) {
      if (pf) {
        if (ptid < 500) qcd[nxt * 500 + ptid] = pqc;
        if (ptid < 300) gi1d[nxt * 300 + ptid] = pgi;
        if (tid >= 924 && tid < 929) qwd[nxt * 8 + tid - 924] = pqw;
        if (tid >= 929 && tid < 939 && (t + 1) > RK_) topd[nxt * 10 + tid - 929] = min(T_ - 1, max(0, ptop));
        if (tid >= 939 && tid < 947 && (t + 2) < T_) cidS[tid - 939] = pci;
        if (tid == 947) { icons[36] = qn2; icons[37] = pqn; }
      }
      if (tid == 948 && (t + 2) < T_) spinflag(&bflags[t + 2]);
      if (t > 0 && ptid < 100) {
        hcomb[100 + ptid] = g2v[ptid];
        g2hist[t * 100 + ptid] = g2v[ptid];
      }
    }
    __syncthreads();  // b3

    // ---- S6: wave-0 kw/softmax/store ----
    if (tid < 64) {
      float v = (tid < 50) ? (kqs[tid] + kqs[tid + 50]) : 0.f;
      v += __shfl_xor(v, 1);
      v += __shfl_xor(v, 2);
      v += __shfl_xor(v, 4);
      v += __shfl_xor(v, 8);
      v += __shfl_xor(v, 16);
      v += __shfl_xor(v, 32);
      const float kw = v;
      float pq = 0.f;
      if (tid < 5) {
        const float qw = qwd[cur * 8 + tid];
        float tmp[11];
        float m = -__builtin_inff();
#pragma unroll
        for (int s = 0; s < 11; ++s) {
          float kws;
          bool valid;
          if (s == 0) { kws = kw; valid = true; }
          else if (t > RK_) { kws = kwhist[topd[cur * 10 + s - 1]]; valid = true; }
          else { valid = (s - 1 < t); kws = kwhist[s - 1]; }
          float tv = valid ? (qw + kws + bWv) : NEGV;
          tmp[s] = tv;
          m = fmaxf(m, tv);
        }
        float den = 0.f, num = 0.f;
#pragma unroll
        for (int s = 0; s < 11; ++s) {
          float e = expf(tmp[s] - m);
          den += e;
          num += e * ogs[cur * 56 + s * 5 + tid];
        }
        pq = num / den;
      }
      if (tid == 5 && t > 0) kwhist[t] = kw;
      float sp = pq;
      sp += __shfl_xor(sp, 1);
      sp += __shfl_xor(sp, 2);
      sp += __shfl_xor(sp, 4);
      if (tid == 0) {
        int col = (t == 0) ? 0 : (t + 1);
        out[b * S_ + col] = sp;
        if (t == 0) out[b * S_ + 1] = 0.f;
      }
    }
  }
}

// ---------------------------------------------------------------------------
extern "C" void kernel_launch(void* const* d_in, const int* in_sizes, int n_in,
                              void* d_out, int out_size, void* d_ws, size_t ws_size,
                              hipStream_t stream)
{
  (void)in_sizes; (void)n_in; (void)out_size; (void)ws_size;
  const float* Eq     = (const float*)d_in[0];
  const float* Ec     = (const float*)d_in[1];
  const float* Er     = (const float*)d_in[2];
  const float* W_ih1  = (const float*)d_in[3];
  const float* W_hh1  = (const float*)d_in[4];
  const float* b_ih1  = (const float*)d_in[5];
  const float* b_hh1  = (const float*)d_in[6];
  const float* W_ih2  = (const float*)d_in[7];
  const float* W_hh2  = (const float*)d_in[8];
  const float* b_ih2  = (const float*)d_in[9];
  const float* b_hh2  = (const float*)d_in[10];
  const float* Wagg   = (const float*)d_in[11];
  const float* bagg   = (const float*)d_in[12];
  const float* W_last = (const float*)d_in[13];
  const float* b_last = (const float*)d_in[14];
  const float* W_query= (const float*)d_in[15];
  const float* b_query= (const float*)d_in[16];
  const float* W_key  = (const float*)d_in[17];
  const float* b_key  = (const float*)d_in[18];
  const float* W_W    = (const float*)d_in[19];
  const float* b_W    = (const float*)d_in[20];
  const float* h1_init= (const float*)d_in[21];
  const float* h2_init= (const float*)d_in[22];
  const int* question = (const int*)d_in[23];
  const int* response = (const int*)d_in[24];
  const int* mask     = (const int*)d_in[25];
  const int* qnb      = (const int*)d_in[26];
  const int* snb      = (const int*)d_in[27];
  const int* cidx     = (const int*)d_in[28];
  const int* cmask    = (const int*)d_in[29];
  float* out = (float*)d_out;

  char* ws = (char*)d_ws;
  size_t off = 0;
  auto alloc = [&](size_t bytes) -> void* {
    void* p = ws + off;
    off += (bytes + 255) & ~(size_t)255;
    return p;
  };
  u32*   wih1a2 = (u32*)alloc(15000 * 4);
  float* erw    = (float*)alloc(600 * 4);
  u32*   wagg2  = (u32*)alloc(15000 * 4);
  u32*   wlast2 = (u32*)alloc(5000 * 4);
  float* wkeyT  = (float*)alloc(10000 * 4);
  float* scal   = (float*)alloc(4);
  u32*   wcat16 = (u32*)alloc(114688 * 4);
  float* bcat   = (float*)alloc(1792 * 4);
  float* gi1_all = (float*)alloc((size_t)B_ * T_ * 300 * 4);
  float* qw_all  = (float*)alloc((size_t)B_ * T_ * 5 * 4);
  int*   top10   = (int*)alloc((size_t)B_ * T_ * 10 * 4);
  int*   flags   = (int*)alloc((size_t)B_ * T_ * 4);

  hipLaunchKernelGGL(setupk, dim3(128), dim3(256), 0, stream,
      Er, W_ih1, b_ih1, Wagg, W_last, W_key, b_query, W_W, W_query,
      W_hh1, W_hh2, W_ih2, b_hh1, b_hh2, b_ih2,
      wih1a2, erw, wagg2, wlast2, wkeyT, scal, wcat16, bcat);

  hipLaunchKernelGGL(megak, dim3(B_ + B_ * T_), dim3(1024), 0, stream,
      wcat16, bcat, wih1a2, erw, wagg2, wlast2, wkeyT,
      gi1_all, qw_all, top10, flags,
      W_W, b_W, b_key, bagg, b_last,
      Eq, Ec, question, response, mask, qnb, snb, cidx, cmask,
      h1_init, h2_init, scal, out);
}

// Round 17
// 1665.738 us; speedup vs baseline: 3.4858x; 1.9571x over previous
//
#include <hip/hip_runtime.h>
#include <hip/hip_bf16.h>
#include <math.h>

typedef unsigned int u32;

#define B_ 128
#define S_ 128
#define T_ 127
#define D_ 100
#define QN_ 4
#define SN_ 4
#define KC_ 4
#define RK_ 10
#define NEGV -1000000000.0f

__device__ __forceinline__ float sigmf(float x) { return 1.0f / (1.0f + expf(-x)); }

__device__ __forceinline__ u32 f2bfbits(float x) {
  __hip_bfloat16 h = __float2bfloat16(x);
  unsigned short s;
  __builtin_memcpy(&s, &h, 2);
  return (u32)s;
}

// ---------------------------------------------------------------------------
// Setup (R13 version): f32 transposed weights for phaseAB; erw fold; kw0;
// bf16 lane-swizzled weight image for seqk (1792 slots x 64 u32 = 256B):
//   [0,300): W_hh1 | [300,600): W_hh2 | [1024,1324): W_ih2 | [1536,1636): W_query
// slot bytes: [sub(4)][k(16 u32)], u32 k packs bf16 cols (sub*25+2k, +2k+1).
// ---------------------------------------------------------------------------
__global__ __launch_bounds__(256) void setupk(
    const float* Er, const float* W_ih1, const float* b_ih1,
    const float* Wagg, const float* W_last, const float* W_key,
    const float* b_query, const float* W_W, const float* W_query,
    const float* W_hh1, const float* W_hh2, const float* W_ih2,
    const float* b_hh1, const float* b_hh2, const float* b_ih2,
    float* wih1aT, float* erw, float* waggT, float* wlastT, float* wkeyT,
    float* scal, u32* wcat16, float* bcat)
{
  int gid = blockIdx.x * blockDim.x + threadIdx.x;
  int gsz = gridDim.x * blockDim.x;

  for (int x = gid; x < 30000; x += gsz) {
    int j = x / 300, i = x % 300;
    wih1aT[j * 300 + i] = W_ih1[i * 200 + j];
  }
  for (int x = gid; x < 600; x += gsz) {
    int r = x / 300, i = x % 300;
    float acc = b_ih1[i];
    for (int j = 0; j < 100; j++) acc += Er[r * 100 + j] * W_ih1[i * 200 + 100 + j];
    erw[x] = acc;
  }
  for (int x = gid; x < 30000; x += gsz) {
    int h = x / 10000, rr = x % 10000, j = rr / 100, i = rr % 100;
    waggT[h * 10000 + j * 100 + i] = Wagg[h * 10000 + i * 100 + j];
  }
  for (int x = gid; x < 10000; x += gsz) {
    int j = x / 100, i = x % 100;
    wlastT[j * 100 + i] = W_last[i * 100 + j];
    wkeyT[j * 100 + i] = W_key[i * 100 + j];
  }
  for (int x = gid; x < 114688; x += gsz) {
    int slot = x / 64, rem = x % 64, sbu = rem / 16, k = rem % 16;
    const float* src = nullptr;
    if (slot < 300)                       src = W_hh1 + (size_t)slot * 100;
    else if (slot < 600)                  src = W_hh2 + (size_t)(slot - 300) * 100;
    else if (slot >= 1024 && slot < 1324) src = W_ih2 + (size_t)(slot - 1024) * 100;
    else if (slot >= 1536 && slot < 1636) src = W_query + (size_t)(slot - 1536) * 100;
    u32 lo = 0, hi = 0;
    if (src) {
      int e0 = 2 * k, e1 = 2 * k + 1;
      if (e0 < 25) lo = f2bfbits(src[sbu * 25 + e0]);
      if (e1 < 25) hi = f2bfbits(src[sbu * 25 + e1]);
    }
    wcat16[x] = (hi << 16) | lo;
  }
  for (int x = gid; x < 1792; x += gsz) {
    float v = 0.f;
    if (x < 300) v = b_hh1[x];
    else if (x < 600) v = b_hh2[x - 300];
    else if (x >= 1024 && x < 1324) v = b_ih2[x - 1024];
    else if (x >= 1536 && x < 1636) v = b_query[x - 1536];
    bcat[x] = v;
  }
  if (gid == 0) {
    float acc = 0.f;  // kw of the all-zero hist state: dot(tanh(b_query), Wk_part)
    for (int i = 0; i < 100; i++) acc += tanhf(b_query[i]) * W_W[100 + i];
    scal[0] = acc;
  }
}

// ---------------------------------------------------------------------------
// Phase A+B fused (one block per (b,t), 256 threads):
//   A: 3-hop aggregate -> gi1 (R13 f32 body);
//   B: qw[5] + top-10 (single-wave butterfly, proven in R14-R16).
// LDS: one 6400-float blob; qcf/qtl/qwp alias the dead e2 region in part B.
// ---------------------------------------------------------------------------
__global__ __launch_bounds__(256) void phaseAB(
    const float* Eq, const float* Ec, const int* question, const int* response, const int* mask,
    const int* qnb, const int* snb,
    const float* wih1aT, const float* erw, const float* waggT, const float* wlastT,
    const float* baggf, const float* blastf, float* gi1_all,
    const int* cidx, const int* cmask, const float* wkeyT, const float* b_key,
    const float* W_W, float* qw_all, int* top10_all)
{
  const int t = blockIdx.x, b = blockIdx.y, tid = threadIdx.x;
  __shared__ __align__(16) float S[6400];
  float* e0 = S;        float* ne0 = S + 100;  float* e1 = S + 200;  float* ne1 = S + 600;
  float* e2 = S + 1000; float* ne2 = S + 2600; float* m3 = S + 4200;
  float* sum4 = S + 5800; float* sum1 = S + 6200; float* emq = S + 6300;
  // part-B aliases (regions dead by then):
  float* qcf = S + 1000; float* qtl = S + 1500; float* qwp = S + 2000;
  __shared__ int l1[4], l2[16], l3[64], ci[4], cm[4];

  const int qt = question[b * S_ + t];
  const int mt = mask[b * S_ + t];
  const int rt = response[b * S_ + t];

  if (mt != 0) {
    if (tid < 4) l1[tid] = qnb[qt * QN_ + tid];
    for (int x = tid; x < 100; x += 256) e0[x] = Eq[(size_t)qt * 100 + x];
    __syncthreads();
    if (tid < 16) l2[tid] = snb[l1[tid >> 2] * SN_ + (tid & 3)];
    for (int x = tid; x < 400; x += 256) e1[x] = Ec[(size_t)l1[x / 100] * 100 + (x % 100)];
    __syncthreads();
    if (tid < 64) l3[tid] = qnb[l2[tid >> 2] * QN_ + (tid & 3)];
    for (int x = tid; x < 1600; x += 256) e2[x] = Eq[(size_t)l2[x / 100] * 100 + (x % 100)];
    __syncthreads();
    for (int x = tid; x < 1600; x += 256) {
      int r = x / 100, j = x % 100;
      const int* lr = l3 + r * 4;
      float s = Ec[(size_t)lr[0] * 100 + j] + Ec[(size_t)lr[1] * 100 + j] +
                Ec[(size_t)lr[2] * 100 + j] + Ec[(size_t)lr[3] * 100 + j];
      m3[x] = e2[x] + 0.25f * s;
    }
    for (int x = tid; x < 100; x += 256)
      sum1[x] = e0[x] + 0.25f * (e1[x] + e1[100 + x] + e1[200 + x] + e1[300 + x]);
    for (int x = tid; x < 400; x += 256) {
      int k = x / 100, j = x % 100;
      const float* e2k = e2 + k * 400;
      sum4[x] = e1[x] + 0.25f * (e2k[j] + e2k[100 + j] + e2k[200 + j] + e2k[300 + j]);
    }
    __syncthreads();
    for (int o = tid; o < 2100; o += 256) {
      const float *in, *W;
      float bia;
      float* dst;
      int i = o % 100;
      if (o < 100)      { in = sum1;                           W = waggT;          bia = baggf[i];       dst = ne0 + o; }
      else if (o < 500) { in = sum4 + ((o - 100) / 100) * 100; W = waggT + 10000;  bia = baggf[100 + i]; dst = ne1 + (o - 100); }
      else              { in = m3 + ((o - 500) / 100) * 100;   W = waggT + 20000;  bia = baggf[200 + i]; dst = ne2 + (o - 500); }
      float acc = bia;
      for (int j = 0; j < 100; j++) acc += in[j] * W[j * 100 + i];
      *dst = tanhf(acc);
    }
    __syncthreads();
    for (int x = tid; x < 100; x += 256)
      sum1[x] = ne0[x] + 0.25f * (ne1[x] + ne1[100 + x] + ne1[200 + x] + ne1[300 + x]);
    for (int x = tid; x < 400; x += 256) {
      int k = x / 100, j = x % 100;
      const float* n2k = ne2 + k * 400;
      sum4[x] = ne1[x] + 0.25f * (n2k[j] + n2k[100 + j] + n2k[200 + j] + n2k[300 + j]);
    }
    __syncthreads();
    for (int o = tid; o < 500; o += 256) {
      int i = o % 100;
      if (o < 100) {
        float acc = baggf[i];
        for (int j = 0; j < 100; j++) acc += sum1[j] * waggT[j * 100 + i];
        e0[i] = tanhf(acc);
      } else {
        const float* in = sum4 + ((o - 100) / 100) * 100;
        float acc = baggf[100 + i];
        for (int j = 0; j < 100; j++) acc += in[j] * waggT[10000 + j * 100 + i];
        e1[o - 100] = tanhf(acc);
      }
    }
    __syncthreads();
    for (int x = tid; x < 100; x += 256)
      sum1[x] = e0[x] + 0.25f * (e1[x] + e1[100 + x] + e1[200 + x] + e1[300 + x]);
    __syncthreads();
    for (int o = tid; o < 100; o += 256) {
      float acc = baggf[o];
      for (int j = 0; j < 100; j++) acc += sum1[j] * waggT[j * 100 + o];
      ne0[o] = tanhf(acc);
    }
    __syncthreads();
    for (int o = tid; o < 100; o += 256) {
      float acc = blastf[o];
      for (int j = 0; j < 100; j++) acc += ne0[j] * wlastT[j * 100 + o];
      emq[o] = tanhf(acc);
    }
    __syncthreads();
  } else {
    for (int x = tid; x < 100; x += 256) emq[x] = Eq[(size_t)qt * 100 + x];
    __syncthreads();
  }

  const size_t bt = (size_t)b * T_ + t;
  for (int o = tid; o < 300; o += 256) {
    float acc = erw[rt * 300 + o];
    for (int j = 0; j < 100; j++) acc += emq[j] * wih1aT[j * 300 + o];
    gi1_all[bt * 300 + o] = acc;
  }

  // ================= part B (aliases e2 region; dead by now) ===============
  const int qn = question[b * S_ + t + 1];
  if (tid < 4) { ci[tid] = cidx[qn * KC_ + tid]; cm[tid] = cmask[qn * KC_ + tid]; }
  __syncthreads();
  for (int u = tid; u < 500; u += 256) {
    int row = u / 100, j = u % 100;
    float v;
    if (row == 0) v = Eq[(size_t)qn * 100 + j];
    else {
      int k = row - 1;
      v = cm[k] ? Ec[(size_t)ci[k] * 100 + j] : 0.f;
    }
    qcf[u] = v;
  }
  __syncthreads();
  for (int o = tid; o < 500; o += 256) {
    int q = o / 100, i = o % 100;
    float acc = b_key[i];
    const float* src = qcf + q * 100;
    for (int j = 0; j < 100; j++) acc += src[j] * wkeyT[j * 100 + i];
    qtl[o] = tanhf(acc);
  }
  __syncthreads();
  if (tid < 20) {
    int q = tid / 4, part = tid % 4;
    float acc = 0.f;
    for (int j = part * 25; j < part * 25 + 25; j++) acc += qtl[q * 100 + j] * W_W[j];
    qwp[tid] = acc;
  }
  __syncthreads();
  if (tid < 5) qw_all[bt * 5 + tid] = qwp[tid * 4] + qwp[tid * 4 + 1] + qwp[tid * 4 + 2] + qwp[tid * 4 + 3];

  if (t > RK_ && tid < 64) {
    const int s0 = tid, s1 = tid + 64;
    float v0 = -__builtin_inff(), v1 = -__builtin_inff();
    if (s0 < t) {
      int qs = question[b * S_ + s0];
      float a = 0.f;
      for (int j = 0; j < 100; j++) a += Eq[(size_t)qs * 100 + j] * qcf[j];
      v0 = a;
    }
    if (s1 < t) {
      int qs = question[b * S_ + s1];
      float a = 0.f;
      for (int j = 0; j < 100; j++) a += Eq[(size_t)qs * 100 + j] * qcf[j];
      v1 = a;
    }
    for (int pass = 0; pass < 10; pass++) {
      float bv; int bi;
      if (v1 > v0) { bv = v1; bi = s1; } else { bv = v0; bi = s0; }  // s0<s1: tie -> s0
#pragma unroll
      for (int off = 1; off < 64; off <<= 1) {
        float ov = __shfl_xor(bv, off);
        int oi = __shfl_xor(bi, off);
        if (ov > bv || (ov == bv && oi < bi)) { bv = ov; bi = oi; }
      }
      if (tid == 0) top10_all[bt * 10 + pass] = bi;
      if (bi == s0) v0 = -__builtin_inff();
      else if (bi == s1) v1 = -__builtin_inff();
    }
  }
}

// bf16 row-dot helper: dot(unpack(w[0..3]), hr[0..31])
__device__ __forceinline__ float bf16_dot32(const uint4 w[4], const float hr[32]) {
  float a = 0.f;
#pragma unroll
  for (int c = 0; c < 4; ++c) {
    uint4 ww = w[c];
    const int e = c * 8;
    a = fmaf(__uint_as_float(ww.x << 16),         hr[e + 0], a);
    a = fmaf(__uint_as_float(ww.x & 0xffff0000u), hr[e + 1], a);
    a = fmaf(__uint_as_float(ww.y << 16),         hr[e + 2], a);
    a = fmaf(__uint_as_float(ww.y & 0xffff0000u), hr[e + 3], a);
    a = fmaf(__uint_as_float(ww.z << 16),         hr[e + 4], a);
    a = fmaf(__uint_as_float(ww.z & 0xffff0000u), hr[e + 5], a);
    a = fmaf(__uint_as_float(ww.w << 16),         hr[e + 6], a);
    a = fmaf(__uint_as_float(ww.w & 0xffff0000u), hr[e + 7], a);
  }
  return a;
}

// ---------------------------------------------------------------------------
// Sequential scan v8 (verbatim R13, the 1636us/931us-passing version):
// 1024 threads, 3 barriers/step, fused matvec+GRU phases, wave-0 tail.
// ---------------------------------------------------------------------------
__global__ __launch_bounds__(1024) void seqk(
    const u32* wcat16, const float* bcat,
    const float* gi1_all, const float* qw_all, const int* top10_all,
    const float* W_W, const float* b_W,
    const float* Eq, const float* Ec, const int* question, const int* cidx, const int* cmask,
    const float* h1_init, const float* h2_init, const float* scal,
    float* out)
{
  const int b = blockIdx.x, tid = threadIdx.x;
  const int grp = tid >> 2, sub = tid & 3;
  const int ptid = tid - 424;
  const uint4* wimg = (const uint4*)wcat16;

  __shared__ float g2hist[T_ * 100];
  __shared__ float hcomb[200];
  __shared__ __align__(16) float h1n[100], g2v[100];
  __shared__ float gh2[300], kqs[100];
  __shared__ float gi1d[2][300];
  __shared__ float qcd[2][500];
  __shared__ float qwd[2][5];
  __shared__ int topd[2][10];
  __shared__ float kwhist[128];
  __shared__ float ogs[2][55];
  __shared__ float bresS[1792];
  __shared__ float wkS[100];
  __shared__ int cidS[8], cid0S[8];
  __shared__ int qn1S, qnS;

  for (int x = tid; x < 1792; x += 1024) bresS[x] = bcat[x];
  if (tid < 100) wkS[tid] = W_W[100 + tid];

  const float bWv = b_W[0];
  const float kw0 = scal[0];

  if (tid < 100) {
    hcomb[tid] = h1_init[b * 100 + tid];
    g2hist[tid] = 0.f;
  } else if (tid < 200) {
    hcomb[tid] = h2_init[b * 100 + (tid - 100)];
  }
  if (tid < 128) kwhist[tid] = kw0;
  if (tid < 300) gi1d[0][tid] = gi1_all[(size_t)b * T_ * 300 + tid];
  if (tid >= 300 && tid < 305) qwd[0][tid - 300] = qw_all[(size_t)b * T_ * 5 + (tid - 300)];
  if (tid == 306) { qn1S = question[b * S_ + 2]; qnS = question[b * S_ + 3]; }
  if (tid >= 320 && tid < 328) {
    int k = tid - 320, qn0 = question[b * S_ + 1];
    cid0S[k] = (k < 4) ? cidx[qn0 * KC_ + k] : cmask[qn0 * KC_ + k - 4];
  }
  if (tid >= 328 && tid < 336) {
    int k = tid - 328, qn1 = question[b * S_ + 2];
    cidS[k] = (k < 4) ? cidx[qn1 * KC_ + k] : cmask[qn1 * KC_ + k - 4];
  }
  __syncthreads();
  if (tid < 500) {
    int q = tid / 100, j = tid % 100;
    int qn0 = question[b * S_ + 1];
    qcd[0][tid] = (q == 0) ? Eq[(size_t)qn0 * 100 + j]
                           : (cid0S[4 + q - 1] ? Ec[(size_t)cid0S[q - 1] * 100 + j] : 0.f);
  }
  __syncthreads();

  for (int t = 0; t < T_; ++t) {
    const size_t bt = (size_t)b * T_ + t;
    const int cur = t & 1, nxt = cur ^ 1;
    const bool pf = (t + 1) < T_;
    const int qn1 = qn1S, qn2 = qnS;

    float pqc = 0.f, pgi = 0.f, pqw = 0.f;
    int ptop = 0, pci = 0, pqn = 0;
    if (pf) {
      if (ptid >= 0 && ptid < 500) {
        int q = ptid / 100, j = ptid % 100;
        pqc = (q == 0) ? Eq[(size_t)qn1 * 100 + j]
                       : (cidS[4 + q - 1] ? Ec[(size_t)cidS[q - 1] * 100 + j] : 0.f);
      }
      if (ptid >= 0 && ptid < 300) pgi = gi1_all[(bt + 1) * 300 + ptid];
      if (tid >= 924 && tid < 929) pqw = qw_all[(bt + 1) * 5 + (tid - 924)];
      if (tid >= 929 && tid < 939 && (t + 1) > RK_) ptop = top10_all[(bt + 1) * 10 + (tid - 929)];
      if (tid >= 939 && tid < 947 && (t + 2) < T_) {
        int k = tid - 939;
        pci = (k < 4) ? cidx[qn2 * KC_ + k] : cmask[qn2 * KC_ + k - 4];
      }
      if (tid == 947) pqn = question[b * S_ + min(t + 4, S_ - 1)];
    }

    // ---- S1: fused gh1+GRU1 | gh2 | og s>=1 ----
    if (grp < 200) {
      const bool g1 = (grp < 100);
      const int j = g1 ? grp : (grp - 100);
      const int s0 = g1 ? j : (300 + j);
      uint4 w0[4], w1[4], w2[4];
      {
        const uint4* p0 = wimg + (size_t)s0 * 16 + sub * 4;
        const uint4* p1 = wimg + (size_t)(s0 + 100) * 16 + sub * 4;
        const uint4* p2 = wimg + (size_t)(s0 + 200) * 16 + sub * 4;
#pragma unroll
        for (int c = 0; c < 4; ++c) { w0[c] = p0[c]; w1[c] = p1[c]; w2[c] = p2[c]; }
      }
      float hr[32];
#pragma unroll
      for (int c = 25; c < 32; ++c) hr[c] = 0.f;
      const int off = g1 ? 0 : 100;
#pragma unroll
      for (int c = 0; c < 25; ++c) hr[c] = hcomb[off + sub * 25 + c];
      float a0 = bf16_dot32(w0, hr);
      float a1 = bf16_dot32(w1, hr);
      float a2 = bf16_dot32(w2, hr);
      a0 += __shfl_xor(a0, 1); a0 += __shfl_xor(a0, 2);
      a1 += __shfl_xor(a1, 1); a1 += __shfl_xor(a1, 2);
      a2 += __shfl_xor(a2, 1); a2 += __shfl_xor(a2, 2);
      if (sub == 0) {
        if (g1) {
          float g0 = a0 + bresS[j], gg1 = a1 + bresS[100 + j], gg2 = a2 + bresS[200 + j];
          float rg = sigmf(gi1d[cur][j] + g0);
          float z  = sigmf(gi1d[cur][100 + j] + gg1);
          float n  = tanhf(gi1d[cur][200 + j] + rg * gg2);
          h1n[j] = (1.f - z) * n + z * hcomb[j];
        } else {
          gh2[j]       = a0 + bresS[300 + j];
          gh2[100 + j] = a1 + bresS[400 + j];
          gh2[200 + j] = a2 + bresS[500 + j];
        }
      }
    } else if (grp < 250) {
      int d = grp - 200;
      int s = 1 + d / 5, q = d % 5;
      bool valid = (t > RK_) || (s - 1 < t);
      float a = 0.f;
      if (valid) {
        int idx = (t > RK_) ? topd[cur][s - 1] : (s - 1);
        const float* qcr = &qcd[cur][q * 100 + sub * 25];
        const float* hrow = &g2hist[idx * 100 + sub * 25];
#pragma unroll
        for (int c = 0; c < 25; ++c) a = fmaf(qcr[c], hrow[c], a);
      }
      a += __shfl_xor(a, 1);
      a += __shfl_xor(a, 2);
      if (sub == 0) ogs[cur][s * 5 + q] = a;
    }
    __syncthreads();  // b1

    // ---- S3: fused gi2+GRU2 -> g2v | h1 copy ----
    if (grp < 100) {
      const int j = grp;
      uint4 w0[4], w1[4], w2[4];
      {
        const uint4* p0 = wimg + (size_t)(1024 + j) * 16 + sub * 4;
        const uint4* p1 = wimg + (size_t)(1124 + j) * 16 + sub * 4;
        const uint4* p2 = wimg + (size_t)(1224 + j) * 16 + sub * 4;
#pragma unroll
        for (int c = 0; c < 4; ++c) { w0[c] = p0[c]; w1[c] = p1[c]; w2[c] = p2[c]; }
      }
      float hr[32];
#pragma unroll
      for (int c = 25; c < 32; ++c) hr[c] = 0.f;
#pragma unroll
      for (int c = 0; c < 25; ++c) hr[c] = h1n[sub * 25 + c];
      float a0 = bf16_dot32(w0, hr);
      float a1 = bf16_dot32(w1, hr);
      float a2 = bf16_dot32(w2, hr);
      a0 += __shfl_xor(a0, 1); a0 += __shfl_xor(a0, 2);
      a1 += __shfl_xor(a1, 1); a1 += __shfl_xor(a1, 2);
      a2 += __shfl_xor(a2, 1); a2 += __shfl_xor(a2, 2);
      if (sub == 0) {
        float i_r = a0 + bresS[1024 + j], i_z = a1 + bresS[1124 + j], i_n = a2 + bresS[1224 + j];
        float rg = sigmf(i_r + gh2[j]);
        float z  = sigmf(i_z + gh2[100 + j]);
        float n  = tanhf(i_n + rg * gh2[200 + j]);
        g2v[j] = (1.f - z) * n + z * hcomb[100 + j];
      }
    } else if (tid >= 400 && tid < 500) {
      hcomb[tid - 400] = h1n[tid - 400];
    }
    __syncthreads();  // b2

    // ---- S5: kq | og s=0 | commits + h2/g2hist ----
    if (grp < 100) {
      float hr[32];
#pragma unroll
      for (int c = 25; c < 32; ++c) hr[c] = 0.f;
#pragma unroll
      for (int c = 0; c < 25; ++c) hr[c] = g2v[sub * 25 + c];
      uint4 wc[4];
      {
        const uint4* wp = wimg + (size_t)(1536 + grp) * 16 + sub * 4;
#pragma unroll
        for (int c = 0; c < 4; ++c) wc[c] = wp[c];
      }
      float a = bf16_dot32(wc, hr);
      a += __shfl_xor(a, 1);
      a += __shfl_xor(a, 2);
      if (sub == 0) kqs[grp] = tanhf(a + bresS[1536 + grp]) * wkS[grp];
    } else if (grp < 105) {
      int q = grp - 100;
      const float* qcr = &qcd[cur][q * 100 + sub * 25];
      float a = 0.f;
#pragma unroll
      for (int c = 0; c < 25; ++c) a = fmaf(qcr[c], g2v[sub * 25 + c], a);
      a += __shfl_xor(a, 1);
      a += __shfl_xor(a, 2);
      if (sub == 0) ogs[cur][q] = a;
    }
    if (ptid >= 0) {
      if (pf) {
        if (ptid < 500) qcd[nxt][ptid] = pqc;
        if (ptid < 300) gi1d[nxt][ptid] = pgi;
        if (tid >= 924 && tid < 929) qwd[nxt][tid - 924] = pqw;
        if (tid >= 929 && tid < 939 && (t + 1) > RK_) topd[nxt][tid - 929] = min(T_ - 1, max(0, ptop));
        if (tid >= 939 && tid < 947 && (t + 2) < T_) cidS[tid - 939] = pci;
        if (tid == 947) { qn1S = qn2; qnS = pqn; }
      }
      if (t > 0 && ptid < 100) {
        hcomb[100 + ptid] = g2v[ptid];
        g2hist[t * 100 + ptid] = g2v[ptid];
      }
    }
    __syncthreads();  // b3

    // ---- S6: wave-0 kw/softmax/store ----
    if (tid < 64) {
      float v = (tid < 50) ? (kqs[tid] + kqs[tid + 50]) : 0.f;
      v += __shfl_xor(v, 1);
      v += __shfl_xor(v, 2);
      v += __shfl_xor(v, 4);
      v += __shfl_xor(v, 8);
      v += __shfl_xor(v, 16);
      v += __shfl_xor(v, 32);
      const float kw = v;
      float pq = 0.f;
      if (tid < 5) {
        const float qw = qwd[cur][tid];
        float tmp[11];
        float m = -__builtin_inff();
#pragma unroll
        for (int s = 0; s < 11; ++s) {
          float kws;
          bool valid;
          if (s == 0) { kws = kw; valid = true; }
          else if (t > RK_) { kws = kwhist[topd[cur][s - 1]]; valid = true; }
          else { valid = (s - 1 < t); kws = kwhist[s - 1]; }
          float tv = valid ? (qw + kws + bWv) : NEGV;
          tmp[s] = tv;
          m = fmaxf(m, tv);
        }
        float den = 0.f, num = 0.f;
#pragma unroll
        for (int s = 0; s < 11; ++s) {
          float e = expf(tmp[s] - m);
          den += e;
          num += e * ogs[cur][s * 5 + tid];
        }
        pq = num / den;
      }
      if (tid == 5 && t > 0) kwhist[t] = kw;
      float sp = pq;
      sp += __shfl_xor(sp, 1);
      sp += __shfl_xor(sp, 2);
      sp += __shfl_xor(sp, 4);
      if (tid == 0) {
        int col = (t == 0) ? 0 : (t + 1);
        out[b * S_ + col] = sp;
        if (t == 0) out[b * S_ + 1] = 0.f;
      }
    }
  }
}

// ---------------------------------------------------------------------------
extern "C" void kernel_launch(void* const* d_in, const int* in_sizes, int n_in,
                              void* d_out, int out_size, void* d_ws, size_t ws_size,
                              hipStream_t stream)
{
  (void)in_sizes; (void)n_in; (void)out_size; (void)ws_size;
  const float* Eq     = (const float*)d_in[0];
  const float* Ec     = (const float*)d_in[1];
  const float* Er     = (const float*)d_in[2];
  const float* W_ih1  = (const float*)d_in[3];
  const float* W_hh1  = (const float*)d_in[4];
  const float* b_ih1  = (const float*)d_in[5];
  const float* b_hh1  = (const float*)d_in[6];
  const float* W_ih2  = (const float*)d_in[7];
  const float* W_hh2  = (const float*)d_in[8];
  const float* b_ih2  = (const float*)d_in[9];
  const float* b_hh2  = (const float*)d_in[10];
  const float* Wagg   = (const float*)d_in[11];
  const float* bagg   = (const float*)d_in[12];
  const float* W_last = (const float*)d_in[13];
  const float* b_last = (const float*)d_in[14];
  const float* W_query= (const float*)d_in[15];
  const float* b_query= (const float*)d_in[16];
  const float* W_key  = (const float*)d_in[17];
  const float* b_key  = (const float*)d_in[18];
  const float* W_W    = (const float*)d_in[19];
  const float* b_W    = (const float*)d_in[20];
  const float* h1_init= (const float*)d_in[21];
  const float* h2_init= (const float*)d_in[22];
  const int* question = (const int*)d_in[23];
  const int* response = (const int*)d_in[24];
  const int* mask     = (const int*)d_in[25];
  const int* qnb      = (const int*)d_in[26];
  const int* snb      = (const int*)d_in[27];
  const int* cidx     = (const int*)d_in[28];
  const int* cmask    = (const int*)d_in[29];
  float* out = (float*)d_out;

  char* ws = (char*)d_ws;
  size_t off = 0;
  auto alloc = [&](size_t bytes) -> void* {
    void* p = ws + off;
    off += (bytes + 255) & ~(size_t)255;
    return p;
  };
  float* wih1aT = (float*)alloc(30000 * 4);
  float* erw    = (float*)alloc(600 * 4);
  float* waggT  = (float*)alloc(30000 * 4);
  float* wlastT = (float*)alloc(10000 * 4);
  float* wkeyT  = (float*)alloc(10000 * 4);
  float* scal   = (float*)alloc(4);
  u32*   wcat16 = (u32*)alloc(114688 * 4);
  float* bcat   = (float*)alloc(1792 * 4);
  float* gi1_all = (float*)alloc((size_t)B_ * T_ * 300 * 4);
  float* qw_all  = (float*)alloc((size_t)B_ * T_ * 5 * 4);
  int*   top10   = (int*)alloc((size_t)B_ * T_ * 10 * 4);

  hipLaunchKernelGGL(setupk, dim3(128), dim3(256), 0, stream,
      Er, W_ih1, b_ih1, Wagg, W_last, W_key, b_query, W_W, W_query,
      W_hh1, W_hh2, W_ih2, b_hh1, b_hh2, b_ih2,
      wih1aT, erw, waggT, wlastT, wkeyT, scal, wcat16, bcat);

  hipLaunchKernelGGL(phaseAB, dim3(T_, B_), dim3(256), 0, stream,
      Eq, Ec, question, response, mask, qnb, snb,
      wih1aT, erw, waggT, wlastT, bagg, b_last, gi1_all,
      cidx, cmask, wkeyT, b_key, W_W, qw_all, top10);

  hipLaunchKernelGGL(seqk, dim3(B_), dim3(1024), 0, stream,
      wcat16, bcat, gi1_all, qw_all, top10, W_W, b_W,
      Eq, Ec, question, cidx, cmask,
      h1_init, h2_init, scal, out);
}